// Round 13
// baseline (82.925 us; speedup 1.0000x reference)
//
#include <hip/hip_runtime.h>
#include <stdint.h>

#define TDIM 4096
#define CDIM 256
#define NMAT 8

typedef __attribute__((ext_vector_type(8))) __bf16 bf16x8;
typedef __attribute__((ext_vector_type(4))) float f32x4;

__device__ __forceinline__ unsigned short f2bf(float f) {
  unsigned int u = __float_as_uint(f);
  return (unsigned short)((u + 0x7FFFu + ((u >> 16) & 1u)) >> 16);
}
__device__ __forceinline__ void g2lds16(const void* g, void* l) {
  __builtin_amdgcn_global_load_lds((__attribute__((address_space(1))) void*)(void*)g,
                                   (__attribute__((address_space(3))) void*)l, 16, 0, 0);
}
__device__ __forceinline__ unsigned long long shfl_xor_u64(unsigned long long v, int m) {
  int lo = __shfl_xor((int)(unsigned int)(v & 0xFFFFFFFFull), m);
  int hi = __shfl_xor((int)(unsigned int)(v >> 32), m);
  return ((unsigned long long)(unsigned int)hi << 32) | (unsigned int)lo;
}

// ---------------- prep (8-matrix): fp32 -> bf16 (hi only) + row sq-norms (fp32) ----------
__global__ __launch_bounds__(256) void prep_kernel(
    const float* __restrict__ xb, const float* __restrict__ xa,
    unsigned short* __restrict__ xhi, float* __restrict__ sq) {
  const int wid = threadIdx.x >> 6, lane = threadIdx.x & 63;
  const int gr = blockIdx.x * 4 + wid;            // global row 0..32767 (mb*4096+row)
  const int mb = gr >> 12;
  const size_t rowoff = (size_t)gr * CDIM;
  const float* src = (mb < 4) ? (xb + rowoff) : (xa + rowoff - (size_t)4 * TDIM * CDIM);

  float4 v = ((const float4*)src)[lane];          // lane covers cols [4*lane, 4*lane+4)
  float vv[4] = {v.x, v.y, v.z, v.w};
  unsigned short h[4];
  float ss = 0.f;
#pragma unroll
  for (int c = 0; c < 4; ++c) {
    h[c] = f2bf(vv[c]);
    ss += vv[c] * vv[c];
  }
  *(ushort4*)&xhi[rowoff + lane * 4] = make_ushort4(h[0], h[1], h[2], h[3]);
#pragma unroll
  for (int off = 32; off; off >>= 1) ss += __shfl_down(ss, off);
  if (lane == 0) sq[gr] = ss;
}

// ---------------- prep (4-matrix / single-source variant for the small-ws path) ----------
__global__ __launch_bounds__(256) void prep4_kernel(
    const float* __restrict__ src0, unsigned short* __restrict__ xhi,
    float* __restrict__ sq4) {
  const int wid = threadIdx.x >> 6, lane = threadIdx.x & 63;
  const int gr = blockIdx.x * 4 + wid;            // local row 0..16383
  const size_t rowoff = (size_t)gr * CDIM;
  float4 v = ((const float4*)(src0 + rowoff))[lane];
  float vv[4] = {v.x, v.y, v.z, v.w};
  unsigned short h[4];
  float ss = 0.f;
#pragma unroll
  for (int c = 0; c < 4; ++c) {
    h[c] = f2bf(vv[c]);
    ss += vv[c] * vv[c];
  }
  *(ushort4*)&xhi[rowoff + lane * 4] = make_ushort4(h[0], h[1], h[2], h[3]);
#pragma unroll
  for (int off = 32; off; off >>= 1) ss += __shfl_down(ss, off);
  if (lane == 0) sq4[gr] = ss;
}

// ---------------- gram: 128x128-tile bf16 MFMA GEMM, K=256 (R8 structure) ----------------
// 4 waves (2x2, wave tile 64x64), 32 KB LDS single-buffered, granule swizzle,
// upper-triangle tiles only (528/matrix), mirror fused, atomic-free edge popcount.
// R13: __launch_bounds__(256, 4) — cap total regs at 512/4 = 128/wave (64 AGPR acc +
// <=64 arch). Rationale (m69): HW wave-slot granularity steps at total regs
// {64/128/256}; R8's 80+64=144 regs land in the (128,256] bucket -> only 2 waves/SIMD
// (the 25% occupancy measured all session). <=128 crosses the bucket -> 4 waves/SIMD
// -> 4 blocks/CU resident (LDS 4x32.5=130<=160 OK), doubling the inter-block overlap
// that R1-R12 established as the binding resource. R4's spill disaster was cap 128 vs
// ~250 needed; here it's 128 vs ~144 — minor one-shot epilogue spills at worst.
__global__ __launch_bounds__(256, 4) void gram_kernel(
    const unsigned short* __restrict__ xhi, const float* __restrict__ sq,
    unsigned long long* __restrict__ adj, unsigned int* __restrict__ edgepart,
    int ep_base, int mb_base, int mbits) {
  __shared__ unsigned short As[128 * 64];   // [row][64 bf16], granule-swizzled: g ^= row&7
  __shared__ unsigned short Bs[128 * 64];
  __shared__ unsigned int wcnt[4];

  const int tid = threadIdx.x;
  const int wid = tid >> 6, lane = tid & 63;
  const int wr = wid >> 1, wc = wid & 1;          // 2x2 waves, each 64x64 out

  // compact upper-tri grid: blockIdx = pair*(2^mbits) + mbl (matrix<->XCD pinning)
  const int mbl = blockIdx.x & ((1 << mbits) - 1);
  const int mb = mb_base + mbl;
  int rem = blockIdx.x >> mbits;                  // 0..527
  int ti = 0;
  while (rem >= 32 - ti) { rem -= 32 - ti; ++ti; }
  const int tj = ti + rem;

  const unsigned short* hi = xhi + (size_t)mbl * TDIM * CDIM;  // xhi indexed by LOCAL mb
  const float* sqm = sq + (size_t)mb * TDIM;                   // sq indexed by GLOBAL mb

  f32x4 acc[4][4] = {};

  const int ldrow = (lane >> 3);                  // 0..7 within 8-row chunk
  const int ldcol = ((lane & 7) ^ ldrow) * 8;     // inverse-swizzled source granule col

  for (int ks = 0; ks < 4; ++ks) {                // K = 256 = 4 x 64
    const int kcol = ks * 64;
    __syncthreads();                               // prev compute done reading LDS
#pragma unroll
    for (int i = 0; i < 4; ++i) {
      const int chunk = wid * 4 + i;               // 16 chunks of 1KB per tile
      const int row = chunk * 8 + ldrow;
      g2lds16(hi + (size_t)(ti * 128 + row) * CDIM + kcol + ldcol, &As[chunk * 512]);
      g2lds16(hi + (size_t)(tj * 128 + row) * CDIM + kcol + ldcol, &Bs[chunk * 512]);
    }
    asm volatile("s_waitcnt vmcnt(0)" ::: "memory");  // staged data landed
    __syncthreads();
#pragma unroll
    for (int kk = 0; kk < 2; ++kk) {
      bf16x8 a[4], b[4];
      const int hi16 = lane >> 4;
#pragma unroll
      for (int m = 0; m < 4; ++m) {
        const int row = wr * 64 + m * 16 + (lane & 15);
        a[m] = *(const bf16x8*)&As[row * 64 + (((kk * 4 + hi16) ^ (row & 7)) * 8)];
      }
#pragma unroll
      for (int n = 0; n < 4; ++n) {
        const int row = wc * 64 + n * 16 + (lane & 15);
        b[n] = *(const bf16x8*)&Bs[row * 64 + (((kk * 4 + hi16) ^ (row & 7)) * 8)];
      }
#pragma unroll
      for (int m = 0; m < 4; ++m)
#pragma unroll
        for (int n = 0; n < 4; ++n)
          acc[m][n] = __builtin_amdgcn_mfma_f32_16x16x32_bf16(a[m], b[n], acc[m][n], 0, 0, 0);
    }
  }

  // epilogue: d2 = sq_i + sq_j - 2*G. Ballots are wave-uniform; lane L captures the
  // assembly for row L (= mtgt*16 + 4*gt + rtgt) at its designated (m,r) iteration.
  const float EPS2 = (float)(22.6 * 22.6);
  unsigned long long* adjm = adj + (size_t)mb * TDIM * 64;   // 64 u64 words per row
  const int gt = (lane >> 2) & 3;
  const int mtgt = lane >> 4, rtgt = lane & 3;
  unsigned long long vrow = 0;

  float4 srv[4];                                  // broadcast loads, L2-hot (16 KB/matrix)
#pragma unroll
  for (int m = 0; m < 4; ++m)
    srv[m] = *(const float4*)&sqm[ti * 128 + wr * 64 + m * 16 + (lane >> 4) * 4];
  float scv[4];
#pragma unroll
  for (int n = 0; n < 4; ++n) scv[n] = sqm[tj * 128 + wc * 64 + n * 16 + (lane & 15)];

#pragma unroll
  for (int m = 0; m < 4; ++m) {
#pragma unroll
    for (int r = 0; r < 4; ++r) {
      const float srr = ((const float*)&srv[m])[r];
      unsigned long long bl[4];
#pragma unroll
      for (int n = 0; n < 4; ++n) {
        const float d2 = srr + scv[n] - 2.0f * acc[m][n][r];
        bl[n] = __ballot(d2 < EPS2);               // bit l <-> (row 4*(l>>4)+r, col n*16+(l&15))
      }
      if (m == mtgt && r == rtgt)
        vrow = ((bl[0] >> (16 * gt)) & 0xFFFFULL)         | (((bl[1] >> (16 * gt)) & 0xFFFFULL) << 16) |
               (((bl[2] >> (16 * gt)) & 0xFFFFULL) << 32) | (((bl[3] >> (16 * gt)) & 0xFFFFULL) << 48);
    }
  }
  // vrow = row `lane` of this wave's 64x64 block: one store for the upper block
  adjm[(size_t)(ti * 128 + wr * 64 + lane) * 64 + tj * 2 + wc] = vrow;

  // fused edge popcount (atomic-free): mirror is a bit-transpose => off-diag counts 2x.
  {
    unsigned int pc = (unsigned int)__popcll(vrow);
#pragma unroll
    for (int off = 32; off; off >>= 1) pc += __shfl_down(pc, off);
    if (lane == 0) wcnt[wid] = (ti != tj) ? pc * 2u : pc;
  }

  // fused mirror: 64x64 bit transpose (butterfly) + store symmetric block
  if (ti != tj) {
    const unsigned long long mk[6] = {
        0x5555555555555555ull, 0x3333333333333333ull, 0x0F0F0F0F0F0F0F0Full,
        0x00FF00FF00FF00FFull, 0x0000FFFF0000FFFFull, 0x00000000FFFFFFFFull};
#pragma unroll
    for (int s = 0; s < 6; ++s) {
      const int d = 1 << s;
      const unsigned long long m = mk[s];
      unsigned long long t = shfl_xor_u64(vrow, d);
      if ((lane & d) == 0) vrow = (vrow & m) | ((t & m) << d);
      else                 vrow = (vrow & ~m) | ((t & ~m) >> d);
    }
    adjm[(size_t)(tj * 128 + wc * 64 + lane) * 64 + ti * 2 + wr] = vrow;
  }

  __syncthreads();
  if (tid == 0)
    edgepart[ep_base + blockIdx.x] = wcnt[0] + wcnt[1] + wcnt[2] + wcnt[3];
}

// ---------------- cc iterate: word-0 seed + min-label propagation + pointer jump ---------
// Warm-start WITHOUT cc_pass1 — seed from adj word 0 only (one coalesced 8B read per
// row; valid since any word-0 bit < 64 <= i, and diag caps rows i<64). Dense graph =>
// nearly every row has a neighbor in cols 0..63, restoring the mn>0 early-exit that
// makes each propagation sweep cheap (R7's identity seed: 1409 us).
__global__ __launch_bounds__(1024) void cc_iter_kernel(const unsigned long long* __restrict__ adj,
                                                       int* __restrict__ ncomp) {
  __shared__ int lab[TDIM];
  __shared__ int nxt[TDIM];
  __shared__ int changed;
  __shared__ int croots;
  const int mb = blockIdx.x;
  const unsigned long long* A = adj + (size_t)mb * TDIM * 64;
  const int tid = threadIdx.x;

  for (int i = tid; i < TDIM; i += 1024) {
    unsigned long long w0 = A[(size_t)i * 64];    // cols 0..63 of row i
    nxt[i] = w0 ? (__ffsll(w0) - 1) : i;          // min word-0 neighbor (<= i always)
  }
  __syncthreads();
  for (int i = tid; i < TDIM; i += 1024) lab[i] = nxt[nxt[i]];  // pointer jump
  __syncthreads();

  for (int it = 0; it < 96; ++it) {
    if (tid == 0) changed = 0;
    __syncthreads();
    for (int i = tid; i < TDIM; i += 1024) {      // one row per thread; label 0 = floor
      const int cur = lab[i];
      int mn = cur;
      if (cur > 0) {
        for (int wd = 0; wd < 64 && mn > 0; ++wd) {
          unsigned long long w = A[(size_t)i * 64 + wd];
          while (w && mn > 0) {
            const int bit = __ffsll(w) - 1;
            w &= w - 1;
            mn = min(mn, lab[wd * 64 + bit]);
          }
        }
        if (mn < cur) changed = 1;                // benign LDS race: all write 1
      }
      nxt[i] = mn;
    }
    __syncthreads();
    const int ch = changed;
    for (int i = tid; i < TDIM; i += 1024) lab[i] = nxt[nxt[i]];  // pointer jump
    __syncthreads();
    if (!ch) break;                               // stable => converged (symmetric adj)
  }

  if (tid == 0) croots = 0;
  __syncthreads();
  int c = 0;
  for (int i = tid; i < TDIM; i += 1024) c += (lab[i] == i);
  atomicAdd(&croots, c);
  __syncthreads();
  if (tid == 0) ncomp[mb] = croots;
}

// ---------------- finalize: sum edge partials; betti = max(0, E - T + C); mean(diff^2) ---
// big=1: one gram launch, blockIdx = pair*8 + mb  -> matrix m at ep[k*8 + m], k<528.
// big=0: two launches of 2112; launch L: ep[L*2112 + pair*4 + (m-4L)].
__global__ __launch_bounds__(512) void final_kernel(const unsigned int* __restrict__ edgepart,
                                                    const int* __restrict__ ncomp,
                                                    float* __restrict__ out, int big) {
  __shared__ unsigned long long es[8];
  const int wid = threadIdx.x >> 6, lane = threadIdx.x & 63;  // wave wid sums matrix wid
  unsigned long long s = 0;
  if (big) {
    for (int k = lane; k < 528; k += 64) s += edgepart[k * 8 + wid];
  } else {
    const int base = (wid < 4) ? 0 : 2112;
    const int m4 = wid & 3;
    for (int k = lane; k < 528; k += 64) s += edgepart[base + k * 4 + m4];
  }
#pragma unroll
  for (int off = 32; off; off >>= 1) s += __shfl_down(s, off);
  if (lane == 0) es[wid] = s;
  __syncthreads();
  if (threadIdx.x == 0) {
    double acc = 0.0;
    for (int b = 0; b < 4; ++b) {
      long long e0 = (long long)(es[b] >> 1);               // sum(adj)//2, diag included
      long long bet0 = e0 - TDIM + (long long)ncomp[b];
      if (bet0 < 0) bet0 = 0;
      long long e1 = (long long)(es[4 + b] >> 1);
      long long bet1 = e1 - TDIM + (long long)ncomp[4 + b];
      if (bet1 < 0) bet1 = 0;
      double d = (double)(bet1 - bet0);
      acc += d * d;
    }
    out[0] = (float)(acc * 0.25);
  }
}

extern "C" void kernel_launch(void* const* d_in, const int* in_sizes, int n_in,
                              void* d_out, int out_size, void* d_ws, size_t ws_size,
                              hipStream_t stream) {
  (void)in_sizes; (void)n_in; (void)out_size;
  const float* xb = (const float*)d_in[0];
  const float* xa = (const float*)d_in[1];
  char* ws = (char*)d_ws;

  // Footprint guard: the 1-shot layout needs ~34 MB. If the harness workspace is
  // smaller, fall back to a ~25.5 MB split pipeline (4-matrix xhi reused across two
  // prep+gram rounds).
  const bool big = (ws_size == 0) || (ws_size >= ((size_t)34 << 20));

  if (big) {
    const size_t XHI_OFF = 0;                                   // 16 MB
    const size_t ADJ_OFF = (size_t)NMAT * TDIM * CDIM * 2;      // 16 MB (8 * 4096 * 64 u64)
    const size_t SQ_OFF  = ADJ_OFF + (size_t)NMAT * TDIM * 64 * 8;
    const size_t NC_OFF  = SQ_OFF + (size_t)NMAT * TDIM * 4;    // ncomp[8]
    const size_t EDGE_OFF = NC_OFF + 64;                        // 4224 u32 (~17 KB)

    unsigned short* xhi = (unsigned short*)(ws + XHI_OFF);
    unsigned long long* adj = (unsigned long long*)(ws + ADJ_OFF);
    float* sq = (float*)(ws + SQ_OFF);
    int* ncomp = (int*)(ws + NC_OFF);
    unsigned int* edgepart = (unsigned int*)(ws + EDGE_OFF);

    prep_kernel<<<NMAT * TDIM / 4, 256, 0, stream>>>(xb, xa, xhi, sq);
    gram_kernel<<<NMAT * 528, 256, 0, stream>>>(xhi, sq, adj, edgepart, 0, 0, 3);
    cc_iter_kernel<<<NMAT, 1024, 0, stream>>>(adj, ncomp);
    final_kernel<<<1, 512, 0, stream>>>(edgepart, ncomp, (float*)d_out, 1);
  } else {
    const size_t XHI_OFF = 0;                                   // 8 MB (4 matrices)
    const size_t ADJ_OFF = (size_t)4 * TDIM * CDIM * 2;         // 8,388,608
    const size_t SQ_OFF  = ADJ_OFF + (size_t)NMAT * TDIM * 64 * 8;  // 25,165,824
    const size_t NC_OFF  = SQ_OFF + (size_t)NMAT * TDIM * 4;
    const size_t EDGE_OFF = NC_OFF + 64;                        // 4224 u32 (~17 KB)

    unsigned short* xhi = (unsigned short*)(ws + XHI_OFF);
    unsigned long long* adj = (unsigned long long*)(ws + ADJ_OFF);
    float* sq = (float*)(ws + SQ_OFF);
    int* ncomp = (int*)(ws + NC_OFF);
    unsigned int* edgepart = (unsigned int*)(ws + EDGE_OFF);

    prep4_kernel<<<TDIM, 256, 0, stream>>>(xb, xhi, sq);                  // matrices 0..3
    gram_kernel<<<4 * 528, 256, 0, stream>>>(xhi, sq, adj, edgepart, 0, 0, 2);
    prep4_kernel<<<TDIM, 256, 0, stream>>>(xa, xhi, sq + (size_t)4 * TDIM);  // matrices 4..7
    gram_kernel<<<4 * 528, 256, 0, stream>>>(xhi, sq, adj, edgepart, 2112, 4, 2);
    cc_iter_kernel<<<NMAT, 1024, 0, stream>>>(adj, ncomp);
    final_kernel<<<1, 512, 0, stream>>>(edgepart, ncomp, (float*)d_out, 0);
  }
}

// Round 14
// 80.881 us; speedup vs baseline: 1.0253x; 1.0253x over previous
//
#include <hip/hip_runtime.h>
#include <stdint.h>

#define TDIM 4096
#define CDIM 256
#define NMAT 8
#define NPAIR 272   // sum over ti of ceil((32-ti)/2)

typedef __attribute__((ext_vector_type(8))) __bf16 bf16x8;
typedef __attribute__((ext_vector_type(4))) float f32x4;

__device__ __forceinline__ unsigned short f2bf(float f) {
  unsigned int u = __float_as_uint(f);
  return (unsigned short)((u + 0x7FFFu + ((u >> 16) & 1u)) >> 16);
}
__device__ __forceinline__ void g2lds16(const void* g, void* l) {
  __builtin_amdgcn_global_load_lds((__attribute__((address_space(1))) void*)(void*)g,
                                   (__attribute__((address_space(3))) void*)l, 16, 0, 0);
}
__device__ __forceinline__ unsigned long long shfl_xor_u64(unsigned long long v, int m) {
  int lo = __shfl_xor((int)(unsigned int)(v & 0xFFFFFFFFull), m);
  int hi = __shfl_xor((int)(unsigned int)(v >> 32), m);
  return ((unsigned long long)(unsigned int)hi << 32) | (unsigned int)lo;
}

// ---------------- prep (8-matrix): fp32 -> bf16 (hi only) + row sq-norms (fp32) ----------
__global__ __launch_bounds__(256) void prep_kernel(
    const float* __restrict__ xb, const float* __restrict__ xa,
    unsigned short* __restrict__ xhi, float* __restrict__ sq) {
  const int wid = threadIdx.x >> 6, lane = threadIdx.x & 63;
  const int gr = blockIdx.x * 4 + wid;            // global row 0..32767 (mb*4096+row)
  const int mb = gr >> 12;
  const size_t rowoff = (size_t)gr * CDIM;
  const float* src = (mb < 4) ? (xb + rowoff) : (xa + rowoff - (size_t)4 * TDIM * CDIM);

  float4 v = ((const float4*)src)[lane];          // lane covers cols [4*lane, 4*lane+4)
  float vv[4] = {v.x, v.y, v.z, v.w};
  unsigned short h[4];
  float ss = 0.f;
#pragma unroll
  for (int c = 0; c < 4; ++c) {
    h[c] = f2bf(vv[c]);
    ss += vv[c] * vv[c];
  }
  *(ushort4*)&xhi[rowoff + lane * 4] = make_ushort4(h[0], h[1], h[2], h[3]);
#pragma unroll
  for (int off = 32; off; off >>= 1) ss += __shfl_down(ss, off);
  if (lane == 0) sq[gr] = ss;
}

// ---------------- prep (4-matrix / single-source variant for the small-ws path) ----------
__global__ __launch_bounds__(256) void prep4_kernel(
    const float* __restrict__ src0, unsigned short* __restrict__ xhi,
    float* __restrict__ sq4) {
  const int wid = threadIdx.x >> 6, lane = threadIdx.x & 63;
  const int gr = blockIdx.x * 4 + wid;            // local row 0..16383
  const size_t rowoff = (size_t)gr * CDIM;
  float4 v = ((const float4*)(src0 + rowoff))[lane];
  float vv[4] = {v.x, v.y, v.z, v.w};
  unsigned short h[4];
  float ss = 0.f;
#pragma unroll
  for (int c = 0; c < 4; ++c) {
    h[c] = f2bf(vv[c]);
    ss += vv[c] * vv[c];
  }
  *(ushort4*)&xhi[rowoff + lane * 4] = make_ushort4(h[0], h[1], h[2], h[3]);
#pragma unroll
  for (int off = 32; off; off >>= 1) ss += __shfl_down(ss, off);
  if (lane == 0) sq4[gr] = ss;
}

// ---------------- gram: 128x256 per block (2 output tiles), K=256, R1-proven sync --------
// R12-exact (measured best: 80.5 us total). Each block computes TWO 128x128 tiles
// (ti, tj0) and (ti, tj0+1). A-tile staged once per K-step for both outputs: 3 tiles
// staged per 2 outputs (-25% L2 traffic) and half the drain/barrier events per output.
// Sync skeleton (single-buffer, __syncthreads, vmcnt(0)) identical to the proven R8
// form. NO register cap beyond (256,2): R13's 128-reg cap spilled the K-loop
// (WRITE_SIZE 19->39 MB, total +2.4 us) — reverted.
__global__ __launch_bounds__(256, 2) void gram_kernel(
    const unsigned short* __restrict__ xhi, const float* __restrict__ sq,
    unsigned long long* __restrict__ adj, unsigned int* __restrict__ edgepart,
    int ep_base, int mb_base, int mbits) {
  __shared__ unsigned short As[128 * 64];      // [row][64 bf16], granule-swizzled
  __shared__ unsigned short Bs[2][128 * 64];   // two B tiles
  __shared__ unsigned int wcnt[4];

  const int tid = threadIdx.x;
  const int wid = tid >> 6, lane = tid & 63;
  const int wr = wid >> 1, wc = wid & 1;          // 2x2 waves, each 64x64 per tile

  // pair grid: blockIdx = pair*(2^mbits) + mbl. Row ti has ceil((32-ti)/2) pair-blocks.
  const int mbl = blockIdx.x & ((1 << mbits) - 1);
  const int mb = mb_base + mbl;
  int rem = blockIdx.x >> mbits;                  // 0..271
  int ti = 0;
  while (rem >= ((33 - ti) >> 1)) { rem -= (33 - ti) >> 1; ++ti; }
  const int tj0 = ti + 2 * rem;
  const int hasT1 = (tj0 < 31);
  const int tj1 = hasT1 ? tj0 + 1 : tj0;          // clamped: safe dup-read, never stored

  const unsigned short* hi = xhi + (size_t)mbl * TDIM * CDIM;  // xhi indexed by LOCAL mb
  const float* sqm = sq + (size_t)mb * TDIM;                   // sq indexed by GLOBAL mb

  f32x4 acc[2][4][4] = {};

  const int ldrow = (lane >> 3);                  // 0..7 within 8-row chunk
  const int ldcol = ((lane & 7) ^ ldrow) * 8;     // inverse-swizzled source granule col

  for (int ks = 0; ks < 4; ++ks) {                // K = 256 = 4 x 64
    const int kcol = ks * 64;
    __syncthreads();                               // prev compute done reading LDS
#pragma unroll
    for (int i = 0; i < 4; ++i) {
      const int chunk = wid * 4 + i;               // 16 chunks of 1KB per tile
      const int row = chunk * 8 + ldrow;
      g2lds16(hi + (size_t)(ti * 128 + row) * CDIM + kcol + ldcol, &As[chunk * 512]);
      g2lds16(hi + (size_t)(tj0 * 128 + row) * CDIM + kcol + ldcol, &Bs[0][chunk * 512]);
      g2lds16(hi + (size_t)(tj1 * 128 + row) * CDIM + kcol + ldcol, &Bs[1][chunk * 512]);
    }
    asm volatile("s_waitcnt vmcnt(0)" ::: "memory");  // staged data landed
    __syncthreads();
#pragma unroll
    for (int kk = 0; kk < 2; ++kk) {
      bf16x8 a[4], b[2][4];
      const int hi16 = lane >> 4;
#pragma unroll
      for (int m = 0; m < 4; ++m) {
        const int row = wr * 64 + m * 16 + (lane & 15);
        a[m] = *(const bf16x8*)&As[row * 64 + (((kk * 4 + hi16) ^ (row & 7)) * 8)];
      }
#pragma unroll
      for (int n = 0; n < 4; ++n) {
        const int row = wc * 64 + n * 16 + (lane & 15);
        const int off = row * 64 + (((kk * 4 + hi16) ^ (row & 7)) * 8);
        b[0][n] = *(const bf16x8*)&Bs[0][off];
        b[1][n] = *(const bf16x8*)&Bs[1][off];
      }
#pragma unroll
      for (int m = 0; m < 4; ++m)
#pragma unroll
        for (int n = 0; n < 4; ++n) {
          acc[0][m][n] = __builtin_amdgcn_mfma_f32_16x16x32_bf16(a[m], b[0][n], acc[0][m][n], 0, 0, 0);
          acc[1][m][n] = __builtin_amdgcn_mfma_f32_16x16x32_bf16(a[m], b[1][n], acc[1][m][n], 0, 0, 0);
        }
    }
  }

  // epilogue per tile: d2 = sq_i + sq_j - 2*G, ballot self-assembly (R8-proven layout).
  const float EPS2 = (float)(22.6 * 22.6);
  unsigned long long* adjm = adj + (size_t)mb * TDIM * 64;   // 64 u64 words per row
  const int gt = (lane >> 2) & 3;
  const int mtgt = lane >> 4, rtgt = lane & 3;

  float4 srv[4];                                  // broadcast loads, L2-hot
#pragma unroll
  for (int m = 0; m < 4; ++m)
    srv[m] = *(const float4*)&sqm[ti * 128 + wr * 64 + m * 16 + (lane >> 4) * 4];
  float scv[2][4];
#pragma unroll
  for (int n = 0; n < 4; ++n) {
    scv[0][n] = sqm[tj0 * 128 + wc * 64 + n * 16 + (lane & 15)];
    scv[1][n] = sqm[tj1 * 128 + wc * 64 + n * 16 + (lane & 15)];
  }

  unsigned int myc = 0;
#pragma unroll
  for (int t = 0; t < 2; ++t) {
    if (t == 0 || hasT1) {                        // wave-uniform guard (block-uniform)
      const int tjt = t ? tj1 : tj0;
      unsigned long long vrow = 0;
#pragma unroll
      for (int m = 0; m < 4; ++m) {
#pragma unroll
        for (int r = 0; r < 4; ++r) {
          const float srr = ((const float*)&srv[m])[r];
          unsigned long long bl[4];
#pragma unroll
          for (int n = 0; n < 4; ++n) {
            const float d2 = srr + scv[t][n] - 2.0f * acc[t][m][n][r];
            bl[n] = __ballot(d2 < EPS2);           // bit l <-> (row 4*(l>>4)+r, col n*16+(l&15))
          }
          if (m == mtgt && r == rtgt)
            vrow = ((bl[0] >> (16 * gt)) & 0xFFFFULL)         | (((bl[1] >> (16 * gt)) & 0xFFFFULL) << 16) |
                   (((bl[2] >> (16 * gt)) & 0xFFFFULL) << 32) | (((bl[3] >> (16 * gt)) & 0xFFFFULL) << 48);
        }
      }
      // row `lane` of this wave's 64x64 block of tile t: one coalesced store
      adjm[(size_t)(ti * 128 + wr * 64 + lane) * 64 + tjt * 2 + wc] = vrow;

      {                                            // fused edge popcount (atomic-free)
        unsigned int pc = (unsigned int)__popcll(vrow);
#pragma unroll
        for (int off = 32; off; off >>= 1) pc += __shfl_down(pc, off);
        if (lane == 0) myc += (ti != tjt) ? pc * 2u : pc;
      }

      if (ti != tjt) {                             // fused mirror: 64x64 bit transpose
        const unsigned long long mk[6] = {
            0x5555555555555555ull, 0x3333333333333333ull, 0x0F0F0F0F0F0F0F0Full,
            0x00FF00FF00FF00FFull, 0x0000FFFF0000FFFFull, 0x00000000FFFFFFFFull};
#pragma unroll
        for (int s = 0; s < 6; ++s) {
          const int d = 1 << s;
          const unsigned long long mkk = mk[s];
          unsigned long long tt = shfl_xor_u64(vrow, d);
          if ((lane & d) == 0) vrow = (vrow & mkk) | ((tt & mkk) << d);
          else                 vrow = (vrow & ~mkk) | ((tt & ~mkk) >> d);
        }
        adjm[(size_t)(tjt * 128 + wc * 64 + lane) * 64 + ti * 2 + wr] = vrow;
      }
    }
  }
  if (lane == 0) wcnt[wid] = myc;

  __syncthreads();
  if (tid == 0)
    edgepart[ep_base + blockIdx.x] = wcnt[0] + wcnt[1] + wcnt[2] + wcnt[3];
}

// ---------------- cc iterate: word-0 seed + min-label propagation + pointer jump ---------
// Warm-start WITHOUT cc_pass1 — seed from adj word 0 only (one coalesced 8B read per
// row; valid since any word-0 bit < 64 <= i, and diag caps rows i<64). Dense graph =>
// nearly every row has a neighbor in cols 0..63, restoring the mn>0 early-exit that
// makes each propagation sweep cheap (R7's identity seed: 1409 us).
__global__ __launch_bounds__(1024) void cc_iter_kernel(const unsigned long long* __restrict__ adj,
                                                       int* __restrict__ ncomp) {
  __shared__ int lab[TDIM];
  __shared__ int nxt[TDIM];
  __shared__ int changed;
  __shared__ int croots;
  const int mb = blockIdx.x;
  const unsigned long long* A = adj + (size_t)mb * TDIM * 64;
  const int tid = threadIdx.x;

  for (int i = tid; i < TDIM; i += 1024) {
    unsigned long long w0 = A[(size_t)i * 64];    // cols 0..63 of row i
    nxt[i] = w0 ? (__ffsll(w0) - 1) : i;          // min word-0 neighbor (<= i always)
  }
  __syncthreads();
  for (int i = tid; i < TDIM; i += 1024) lab[i] = nxt[nxt[i]];  // pointer jump
  __syncthreads();

  for (int it = 0; it < 96; ++it) {
    if (tid == 0) changed = 0;
    __syncthreads();
    for (int i = tid; i < TDIM; i += 1024) {      // one row per thread; label 0 = floor
      const int cur = lab[i];
      int mn = cur;
      if (cur > 0) {
        for (int wd = 0; wd < 64 && mn > 0; ++wd) {
          unsigned long long w = A[(size_t)i * 64 + wd];
          while (w && mn > 0) {
            const int bit = __ffsll(w) - 1;
            w &= w - 1;
            mn = min(mn, lab[wd * 64 + bit]);
          }
        }
        if (mn < cur) changed = 1;                // benign LDS race: all write 1
      }
      nxt[i] = mn;
    }
    __syncthreads();
    const int ch = changed;
    for (int i = tid; i < TDIM; i += 1024) lab[i] = nxt[nxt[i]];  // pointer jump
    __syncthreads();
    if (!ch) break;                               // stable => converged (symmetric adj)
  }

  if (tid == 0) croots = 0;
  __syncthreads();
  int c = 0;
  for (int i = tid; i < TDIM; i += 1024) c += (lab[i] == i);
  atomicAdd(&croots, c);
  __syncthreads();
  if (tid == 0) ncomp[mb] = croots;
}

// ---------------- finalize: sum edge partials; betti = max(0, E - T + C); mean(diff^2) ---
// big=1: one gram launch, blockIdx = pair*8 + mb  -> matrix m at ep[k*8 + m], k<272.
// big=0: two launches of 1088; launch L: ep[L*1088 + k*4 + (m-4L)], k<272.
__global__ __launch_bounds__(512) void final_kernel(const unsigned int* __restrict__ edgepart,
                                                    const int* __restrict__ ncomp,
                                                    float* __restrict__ out, int big) {
  __shared__ unsigned long long es[8];
  const int wid = threadIdx.x >> 6, lane = threadIdx.x & 63;  // wave wid sums matrix wid
  unsigned long long s = 0;
  if (big) {
    for (int k = lane; k < NPAIR; k += 64) s += edgepart[k * 8 + wid];
  } else {
    const int base = (wid < 4) ? 0 : 4 * NPAIR;
    const int m4 = wid & 3;
    for (int k = lane; k < NPAIR; k += 64) s += edgepart[base + k * 4 + m4];
  }
#pragma unroll
  for (int off = 32; off; off >>= 1) s += __shfl_down(s, off);
  if (lane == 0) es[wid] = s;
  __syncthreads();
  if (threadIdx.x == 0) {
    double acc = 0.0;
    for (int b = 0; b < 4; ++b) {
      long long e0 = (long long)(es[b] >> 1);               // sum(adj)//2, diag included
      long long bet0 = e0 - TDIM + (long long)ncomp[b];
      if (bet0 < 0) bet0 = 0;
      long long e1 = (long long)(es[4 + b] >> 1);
      long long bet1 = e1 - TDIM + (long long)ncomp[4 + b];
      if (bet1 < 0) bet1 = 0;
      double d = (double)(bet1 - bet0);
      acc += d * d;
    }
    out[0] = (float)(acc * 0.25);
  }
}

extern "C" void kernel_launch(void* const* d_in, const int* in_sizes, int n_in,
                              void* d_out, int out_size, void* d_ws, size_t ws_size,
                              hipStream_t stream) {
  (void)in_sizes; (void)n_in; (void)out_size;
  const float* xb = (const float*)d_in[0];
  const float* xa = (const float*)d_in[1];
  char* ws = (char*)d_ws;

  // Footprint guard: the 1-shot layout needs ~34 MB. If the harness workspace is
  // smaller, fall back to a ~25.5 MB split pipeline (4-matrix xhi reused across two
  // prep+gram rounds).
  const bool big = (ws_size == 0) || (ws_size >= ((size_t)34 << 20));

  if (big) {
    const size_t XHI_OFF = 0;                                   // 16 MB
    const size_t ADJ_OFF = (size_t)NMAT * TDIM * CDIM * 2;      // 16 MB (8 * 4096 * 64 u64)
    const size_t SQ_OFF  = ADJ_OFF + (size_t)NMAT * TDIM * 64 * 8;
    const size_t NC_OFF  = SQ_OFF + (size_t)NMAT * TDIM * 4;    // ncomp[8]
    const size_t EDGE_OFF = NC_OFF + 64;                        // 2176 u32 (~8.5 KB)

    unsigned short* xhi = (unsigned short*)(ws + XHI_OFF);
    unsigned long long* adj = (unsigned long long*)(ws + ADJ_OFF);
    float* sq = (float*)(ws + SQ_OFF);
    int* ncomp = (int*)(ws + NC_OFF);
    unsigned int* edgepart = (unsigned int*)(ws + EDGE_OFF);

    prep_kernel<<<NMAT * TDIM / 4, 256, 0, stream>>>(xb, xa, xhi, sq);
    gram_kernel<<<NMAT * NPAIR, 256, 0, stream>>>(xhi, sq, adj, edgepart, 0, 0, 3);
    cc_iter_kernel<<<NMAT, 1024, 0, stream>>>(adj, ncomp);
    final_kernel<<<1, 512, 0, stream>>>(edgepart, ncomp, (float*)d_out, 1);
  } else {
    const size_t XHI_OFF = 0;                                   // 8 MB (4 matrices)
    const size_t ADJ_OFF = (size_t)4 * TDIM * CDIM * 2;         // 8,388,608
    const size_t SQ_OFF  = ADJ_OFF + (size_t)NMAT * TDIM * 64 * 8;  // 25,165,824
    const size_t NC_OFF  = SQ_OFF + (size_t)NMAT * TDIM * 4;
    const size_t EDGE_OFF = NC_OFF + 64;                        // 2176 u32 (~8.5 KB)

    unsigned short* xhi = (unsigned short*)(ws + XHI_OFF);
    unsigned long long* adj = (unsigned long long*)(ws + ADJ_OFF);
    float* sq = (float*)(ws + SQ_OFF);
    int* ncomp = (int*)(ws + NC_OFF);
    unsigned int* edgepart = (unsigned int*)(ws + EDGE_OFF);

    prep4_kernel<<<TDIM, 256, 0, stream>>>(xb, xhi, sq);                  // matrices 0..3
    gram_kernel<<<4 * NPAIR, 256, 0, stream>>>(xhi, sq, adj, edgepart, 0, 0, 2);
    prep4_kernel<<<TDIM, 256, 0, stream>>>(xa, xhi, sq + (size_t)4 * TDIM);  // matrices 4..7
    gram_kernel<<<4 * NPAIR, 256, 0, stream>>>(xhi, sq, adj, edgepart, 4 * NPAIR, 4, 2);
    cc_iter_kernel<<<NMAT, 1024, 0, stream>>>(adj, ncomp);
    final_kernel<<<1, 512, 0, stream>>>(edgepart, ncomp, (float*)d_out, 0);
  }
}

// Round 15
// 79.320 us; speedup vs baseline: 1.0455x; 1.0197x over previous
//
#include <hip/hip_runtime.h>
#include <stdint.h>

#define TDIM 4096
#define CDIM 256
#define NMAT 8
#define NPAIR 272   // sum over ti of ceil((32-ti)/2)

typedef __attribute__((ext_vector_type(8))) __bf16 bf16x8;
typedef __attribute__((ext_vector_type(4))) float f32x4;

__device__ __forceinline__ unsigned short f2bf(float f) {
  unsigned int u = __float_as_uint(f);
  return (unsigned short)((u + 0x7FFFu + ((u >> 16) & 1u)) >> 16);
}
__device__ __forceinline__ void g2lds16(const void* g, void* l) {
  __builtin_amdgcn_global_load_lds((__attribute__((address_space(1))) void*)(void*)g,
                                   (__attribute__((address_space(3))) void*)l, 16, 0, 0);
}
__device__ __forceinline__ unsigned long long shfl_xor_u64(unsigned long long v, int m) {
  int lo = __shfl_xor((int)(unsigned int)(v & 0xFFFFFFFFull), m);
  int hi = __shfl_xor((int)(unsigned int)(v >> 32), m);
  return ((unsigned long long)(unsigned int)hi << 32) | (unsigned int)lo;
}

// ---------------- prep (8-matrix): fp32 -> bf16 (hi only) + row sq-norms (fp32) ----------
__global__ __launch_bounds__(256) void prep_kernel(
    const float* __restrict__ xb, const float* __restrict__ xa,
    unsigned short* __restrict__ xhi, float* __restrict__ sq) {
  const int wid = threadIdx.x >> 6, lane = threadIdx.x & 63;
  const int gr = blockIdx.x * 4 + wid;            // global row 0..32767 (mb*4096+row)
  const int mb = gr >> 12;
  const size_t rowoff = (size_t)gr * CDIM;
  const float* src = (mb < 4) ? (xb + rowoff) : (xa + rowoff - (size_t)4 * TDIM * CDIM);

  float4 v = ((const float4*)src)[lane];          // lane covers cols [4*lane, 4*lane+4)
  float vv[4] = {v.x, v.y, v.z, v.w};
  unsigned short h[4];
  float ss = 0.f;
#pragma unroll
  for (int c = 0; c < 4; ++c) {
    h[c] = f2bf(vv[c]);
    ss += vv[c] * vv[c];
  }
  *(ushort4*)&xhi[rowoff + lane * 4] = make_ushort4(h[0], h[1], h[2], h[3]);
#pragma unroll
  for (int off = 32; off; off >>= 1) ss += __shfl_down(ss, off);
  if (lane == 0) sq[gr] = ss;
}

// ---------------- prep (4-matrix / single-source variant for the small-ws path) ----------
__global__ __launch_bounds__(256) void prep4_kernel(
    const float* __restrict__ src0, unsigned short* __restrict__ xhi,
    float* __restrict__ sq4) {
  const int wid = threadIdx.x >> 6, lane = threadIdx.x & 63;
  const int gr = blockIdx.x * 4 + wid;            // local row 0..16383
  const size_t rowoff = (size_t)gr * CDIM;
  float4 v = ((const float4*)(src0 + rowoff))[lane];
  float vv[4] = {v.x, v.y, v.z, v.w};
  unsigned short h[4];
  float ss = 0.f;
#pragma unroll
  for (int c = 0; c < 4; ++c) {
    h[c] = f2bf(vv[c]);
    ss += vv[c] * vv[c];
  }
  *(ushort4*)&xhi[rowoff + lane * 4] = make_ushort4(h[0], h[1], h[2], h[3]);
#pragma unroll
  for (int off = 32; off; off >>= 1) ss += __shfl_down(ss, off);
  if (lane == 0) sq4[gr] = ss;
}

// ---------------- gram: 128x256 per block, 8 WAVES (R15), K=256, R1-proven sync ----------
// R15: R12's 2-tile staging amortization (3 tiles staged per 2 output tiles, -25%
// traffic, half the drains per output) but with 512 threads / 8 waves — each wave owns
// ONE 64x64 quadrant of ONE tile. Per-wave acc = 64 AGPR (vs R12's 128) -> total regs
// ~148/wave, NO cap, NO spills (the clean version of R13's occupancy experiment).
// LDS 48KB -> 3 blocks/CU by LDS (144<=160), 24 waves/CU possible vs R12's 8.
// Sync skeleton identical: {sync; stage; vmcnt(0)+sync; compute} x 4.
__global__ __launch_bounds__(512, 4) void gram_kernel(
    const unsigned short* __restrict__ xhi, const float* __restrict__ sq,
    unsigned long long* __restrict__ adj, unsigned int* __restrict__ edgepart,
    int ep_base, int mb_base, int mbits) {
  __shared__ unsigned short lds[3 * 128 * 64];  // [tile][row][64]: 0=A(ti),1=B(tj0),2=B(tj1)
  __shared__ unsigned int wcnt[8];

  const int tid = threadIdx.x;
  const int wid = tid >> 6, lane = tid & 63;
  const int wr = wid >> 2;                        // 0..1: row half of the 128
  const int wcq = wid & 3;                        // 0..3: col quadrant across 2 tiles
  const int t = wcq >> 1, wc = wcq & 1;           // tile select, col half within tile

  // pair grid: blockIdx = pair*(2^mbits) + mbl. Row ti has ceil((32-ti)/2) pair-blocks.
  const int mbl = blockIdx.x & ((1 << mbits) - 1);
  const int mb = mb_base + mbl;
  int rem = blockIdx.x >> mbits;                  // 0..271
  int ti = 0;
  while (rem >= ((33 - ti) >> 1)) { rem -= (33 - ti) >> 1; ++ti; }
  const int tj0 = ti + 2 * rem;
  const int hasT1 = (tj0 < 31);
  const int tj1 = hasT1 ? tj0 + 1 : tj0;          // clamped: safe dup-read, never stored

  const unsigned short* hi = xhi + (size_t)mbl * TDIM * CDIM;  // xhi indexed by LOCAL mb
  const float* sqm = sq + (size_t)mb * TDIM;                   // sq indexed by GLOBAL mb

  f32x4 acc[4][4] = {};                           // 64 AGPR per wave

  const int ldrow = (lane >> 3);                  // 0..7 within 8-row chunk
  const int ldcol = ((lane & 7) ^ ldrow) * 8;     // inverse-swizzled source granule col

  for (int ks = 0; ks < 4; ++ks) {                // K = 256 = 4 x 64
    const int kcol = ks * 64;
    __syncthreads();                               // prev compute done reading LDS
#pragma unroll
    for (int i = 0; i < 6; ++i) {                  // 48 chunks of 1KB over 8 waves
      const int c = wid * 6 + i;
      const int tile = c >> 4, cit = c & 15;
      const int trow = (tile == 0) ? ti : ((tile == 1) ? tj0 : tj1);  // wave-uniform sel
      const int row = cit * 8 + ldrow;
      g2lds16(hi + (size_t)(trow * 128 + row) * CDIM + kcol + ldcol,
              &lds[tile * 8192 + cit * 512]);
    }
    asm volatile("s_waitcnt vmcnt(0)" ::: "memory");  // staged data landed
    __syncthreads();
#pragma unroll
    for (int kk = 0; kk < 2; ++kk) {
      bf16x8 a[4], b[4];
      const int hi16 = lane >> 4;
#pragma unroll
      for (int m = 0; m < 4; ++m) {
        const int row = wr * 64 + m * 16 + (lane & 15);
        a[m] = *(const bf16x8*)&lds[row * 64 + (((kk * 4 + hi16) ^ (row & 7)) * 8)];
      }
#pragma unroll
      for (int n = 0; n < 4; ++n) {
        const int row = wc * 64 + n * 16 + (lane & 15);
        b[n] = *(const bf16x8*)&lds[(1 + t) * 8192 + row * 64 +
                                    (((kk * 4 + hi16) ^ (row & 7)) * 8)];
      }
#pragma unroll
      for (int m = 0; m < 4; ++m)
#pragma unroll
        for (int n = 0; n < 4; ++n)
          acc[m][n] = __builtin_amdgcn_mfma_f32_16x16x32_bf16(a[m], b[n], acc[m][n], 0, 0, 0);
    }
  }

  // epilogue (R8-proven per-wave form): this wave's 64x64 block of tile t.
  const float EPS2 = (float)(22.6 * 22.6);
  unsigned long long* adjm = adj + (size_t)mb * TDIM * 64;   // 64 u64 words per row
  const int gt = (lane >> 2) & 3;
  const int mtgt = lane >> 4, rtgt = lane & 3;
  const int tjt = t ? tj1 : tj0;
  const int active = (t == 0) || hasT1;           // block-uniform per wave

  unsigned int myc = 0;
  if (active) {
    float4 srv[4];                                // broadcast loads, L2-hot
#pragma unroll
    for (int m = 0; m < 4; ++m)
      srv[m] = *(const float4*)&sqm[ti * 128 + wr * 64 + m * 16 + (lane >> 4) * 4];
    float scv[4];
#pragma unroll
    for (int n = 0; n < 4; ++n) scv[n] = sqm[tjt * 128 + wc * 64 + n * 16 + (lane & 15)];

    unsigned long long vrow = 0;
#pragma unroll
    for (int m = 0; m < 4; ++m) {
#pragma unroll
      for (int r = 0; r < 4; ++r) {
        const float srr = ((const float*)&srv[m])[r];
        unsigned long long bl[4];
#pragma unroll
        for (int n = 0; n < 4; ++n) {
          const float d2 = srr + scv[n] - 2.0f * acc[m][n][r];
          bl[n] = __ballot(d2 < EPS2);             // bit l <-> (row 4*(l>>4)+r, col n*16+(l&15))
        }
        if (m == mtgt && r == rtgt)
          vrow = ((bl[0] >> (16 * gt)) & 0xFFFFULL)         | (((bl[1] >> (16 * gt)) & 0xFFFFULL) << 16) |
                 (((bl[2] >> (16 * gt)) & 0xFFFFULL) << 32) | (((bl[3] >> (16 * gt)) & 0xFFFFULL) << 48);
      }
    }
    // row `lane` of this wave's 64x64 block: one coalesced store
    adjm[(size_t)(ti * 128 + wr * 64 + lane) * 64 + tjt * 2 + wc] = vrow;

    {                                              // fused edge popcount (atomic-free)
      unsigned int pc = (unsigned int)__popcll(vrow);
#pragma unroll
      for (int off = 32; off; off >>= 1) pc += __shfl_down(pc, off);
      myc = (ti != tjt) ? pc * 2u : pc;            // valid on lane 0
    }

    if (ti != tjt) {                               // fused mirror: 64x64 bit transpose
      const unsigned long long mk[6] = {
          0x5555555555555555ull, 0x3333333333333333ull, 0x0F0F0F0F0F0F0F0Full,
          0x00FF00FF00FF00FFull, 0x0000FFFF0000FFFFull, 0x00000000FFFFFFFFull};
#pragma unroll
      for (int s = 0; s < 6; ++s) {
        const int d = 1 << s;
        const unsigned long long mkk = mk[s];
        unsigned long long tt = shfl_xor_u64(vrow, d);
        if ((lane & d) == 0) vrow = (vrow & mkk) | ((tt & mkk) << d);
        else                 vrow = (vrow & ~mkk) | ((tt & ~mkk) >> d);
      }
      adjm[(size_t)(tjt * 128 + wc * 64 + lane) * 64 + ti * 2 + wr] = vrow;
    }
  }
  if (lane == 0) wcnt[wid] = myc;

  __syncthreads();
  if (tid == 0)
    edgepart[ep_base + blockIdx.x] = wcnt[0] + wcnt[1] + wcnt[2] + wcnt[3] +
                                     wcnt[4] + wcnt[5] + wcnt[6] + wcnt[7];
}

// ---------------- cc iterate: word-0 seed + min-label propagation + pointer jump ---------
// Warm-start WITHOUT cc_pass1 — seed from adj word 0 only (one coalesced 8B read per
// row; valid since any word-0 bit < 64 <= i, and diag caps rows i<64). Dense graph =>
// nearly every row has a neighbor in cols 0..63, restoring the mn>0 early-exit that
// makes each propagation sweep cheap (R7's identity seed: 1409 us).
__global__ __launch_bounds__(1024) void cc_iter_kernel(const unsigned long long* __restrict__ adj,
                                                       int* __restrict__ ncomp) {
  __shared__ int lab[TDIM];
  __shared__ int nxt[TDIM];
  __shared__ int changed;
  __shared__ int croots;
  const int mb = blockIdx.x;
  const unsigned long long* A = adj + (size_t)mb * TDIM * 64;
  const int tid = threadIdx.x;

  for (int i = tid; i < TDIM; i += 1024) {
    unsigned long long w0 = A[(size_t)i * 64];    // cols 0..63 of row i
    nxt[i] = w0 ? (__ffsll(w0) - 1) : i;          // min word-0 neighbor (<= i always)
  }
  __syncthreads();
  for (int i = tid; i < TDIM; i += 1024) lab[i] = nxt[nxt[i]];  // pointer jump
  __syncthreads();

  for (int it = 0; it < 96; ++it) {
    if (tid == 0) changed = 0;
    __syncthreads();
    for (int i = tid; i < TDIM; i += 1024) {      // one row per thread; label 0 = floor
      const int cur = lab[i];
      int mn = cur;
      if (cur > 0) {
        for (int wd = 0; wd < 64 && mn > 0; ++wd) {
          unsigned long long w = A[(size_t)i * 64 + wd];
          while (w && mn > 0) {
            const int bit = __ffsll(w) - 1;
            w &= w - 1;
            mn = min(mn, lab[wd * 64 + bit]);
          }
        }
        if (mn < cur) changed = 1;                // benign LDS race: all write 1
      }
      nxt[i] = mn;
    }
    __syncthreads();
    const int ch = changed;
    for (int i = tid; i < TDIM; i += 1024) lab[i] = nxt[nxt[i]];  // pointer jump
    __syncthreads();
    if (!ch) break;                               // stable => converged (symmetric adj)
  }

  if (tid == 0) croots = 0;
  __syncthreads();
  int c = 0;
  for (int i = tid; i < TDIM; i += 1024) c += (lab[i] == i);
  atomicAdd(&croots, c);
  __syncthreads();
  if (tid == 0) ncomp[mb] = croots;
}

// ---------------- finalize: sum edge partials; betti = max(0, E - T + C); mean(diff^2) ---
// big=1: one gram launch, blockIdx = pair*8 + mb  -> matrix m at ep[k*8 + m], k<272.
// big=0: two launches of 1088; launch L: ep[L*1088 + k*4 + (m-4L)], k<272.
__global__ __launch_bounds__(512) void final_kernel(const unsigned int* __restrict__ edgepart,
                                                    const int* __restrict__ ncomp,
                                                    float* __restrict__ out, int big) {
  __shared__ unsigned long long es[8];
  const int wid = threadIdx.x >> 6, lane = threadIdx.x & 63;  // wave wid sums matrix wid
  unsigned long long s = 0;
  if (big) {
    for (int k = lane; k < NPAIR; k += 64) s += edgepart[k * 8 + wid];
  } else {
    const int base = (wid < 4) ? 0 : 4 * NPAIR;
    const int m4 = wid & 3;
    for (int k = lane; k < NPAIR; k += 64) s += edgepart[base + k * 4 + m4];
  }
#pragma unroll
  for (int off = 32; off; off >>= 1) s += __shfl_down(s, off);
  if (lane == 0) es[wid] = s;
  __syncthreads();
  if (threadIdx.x == 0) {
    double acc = 0.0;
    for (int b = 0; b < 4; ++b) {
      long long e0 = (long long)(es[b] >> 1);               // sum(adj)//2, diag included
      long long bet0 = e0 - TDIM + (long long)ncomp[b];
      if (bet0 < 0) bet0 = 0;
      long long e1 = (long long)(es[4 + b] >> 1);
      long long bet1 = e1 - TDIM + (long long)ncomp[4 + b];
      if (bet1 < 0) bet1 = 0;
      double d = (double)(bet1 - bet0);
      acc += d * d;
    }
    out[0] = (float)(acc * 0.25);
  }
}

extern "C" void kernel_launch(void* const* d_in, const int* in_sizes, int n_in,
                              void* d_out, int out_size, void* d_ws, size_t ws_size,
                              hipStream_t stream) {
  (void)in_sizes; (void)n_in; (void)out_size;
  const float* xb = (const float*)d_in[0];
  const float* xa = (const float*)d_in[1];
  char* ws = (char*)d_ws;

  // Footprint guard: the 1-shot layout needs ~34 MB. If the harness workspace is
  // smaller, fall back to a ~25.5 MB split pipeline (4-matrix xhi reused across two
  // prep+gram rounds).
  const bool big = (ws_size == 0) || (ws_size >= ((size_t)34 << 20));

  if (big) {
    const size_t XHI_OFF = 0;                                   // 16 MB
    const size_t ADJ_OFF = (size_t)NMAT * TDIM * CDIM * 2;      // 16 MB (8 * 4096 * 64 u64)
    const size_t SQ_OFF  = ADJ_OFF + (size_t)NMAT * TDIM * 64 * 8;
    const size_t NC_OFF  = SQ_OFF + (size_t)NMAT * TDIM * 4;    // ncomp[8]
    const size_t EDGE_OFF = NC_OFF + 64;                        // 2176 u32 (~8.5 KB)

    unsigned short* xhi = (unsigned short*)(ws + XHI_OFF);
    unsigned long long* adj = (unsigned long long*)(ws + ADJ_OFF);
    float* sq = (float*)(ws + SQ_OFF);
    int* ncomp = (int*)(ws + NC_OFF);
    unsigned int* edgepart = (unsigned int*)(ws + EDGE_OFF);

    prep_kernel<<<NMAT * TDIM / 4, 256, 0, stream>>>(xb, xa, xhi, sq);
    gram_kernel<<<NMAT * NPAIR, 512, 0, stream>>>(xhi, sq, adj, edgepart, 0, 0, 3);
    cc_iter_kernel<<<NMAT, 1024, 0, stream>>>(adj, ncomp);
    final_kernel<<<1, 512, 0, stream>>>(edgepart, ncomp, (float*)d_out, 1);
  } else {
    const size_t XHI_OFF = 0;                                   // 8 MB (4 matrices)
    const size_t ADJ_OFF = (size_t)4 * TDIM * CDIM * 2;         // 8,388,608
    const size_t SQ_OFF  = ADJ_OFF + (size_t)NMAT * TDIM * 64 * 8;  // 25,165,824
    const size_t NC_OFF  = SQ_OFF + (size_t)NMAT * TDIM * 4;
    const size_t EDGE_OFF = NC_OFF + 64;                        // 2176 u32 (~8.5 KB)

    unsigned short* xhi = (unsigned short*)(ws + XHI_OFF);
    unsigned long long* adj = (unsigned long long*)(ws + ADJ_OFF);
    float* sq = (float*)(ws + SQ_OFF);
    int* ncomp = (int*)(ws + NC_OFF);
    unsigned int* edgepart = (unsigned int*)(ws + EDGE_OFF);

    prep4_kernel<<<TDIM, 256, 0, stream>>>(xb, xhi, sq);                  // matrices 0..3
    gram_kernel<<<4 * NPAIR, 512, 0, stream>>>(xhi, sq, adj, edgepart, 0, 0, 2);
    prep4_kernel<<<TDIM, 256, 0, stream>>>(xa, xhi, sq + (size_t)4 * TDIM);  // matrices 4..7
    gram_kernel<<<4 * NPAIR, 512, 0, stream>>>(xhi, sq, adj, edgepart, 4 * NPAIR, 4, 2);
    cc_iter_kernel<<<NMAT, 1024, 0, stream>>>(adj, ncomp);
    final_kernel<<<1, 512, 0, stream>>>(edgepart, ncomp, (float*)d_out, 0);
  }
}